// Round 6
// baseline (10420.129 us; speedup 1.0000x reference)
//
#include <hip/hip_runtime.h>

// LSTM char-RNN scan: B=512, SEQ=1024, UNITS=256, NUM_CHARS=128. fp32 in/out.
// Round 5: GEMM moved to matrix cores. Round-4/5 was VALU-issue-bound (92%).
//  - pack kernel rewrites W_h (bf16 RNE) into exact MFMA B-fragment streaming
//    order: one coalesced global_load_dwordx4 per lane per 16x16x32 tile,
//    no LDS staging, no unpack VALU.
//  - h kept fp32; A-operand built as hi/lo bf16 split (2 MFMAs) so the
//    recurrence sees effectively-fp32 h. Only W_h is quantized (as round 3-5,
//    measured absmax 4.9e-4).
//  - G2 laid out [row][col] (stride-4B update reads, conflict-free);
//    h2 rows padded +8 bf16 so A-frag ds_read_b128 is 2-way-aliased (free).
// Budget/step/CU: VMEM 512 KB from L2 ~8.7k cyc (binding); MFMA ~1.3k; VALU ~1k.

#define B_TOT   512
#define SEQ     1024
#define U       256
#define NC      128
#define GDIM    1024      // 4*U
#define BC      2
#define THREADS 512       // 8 waves
#define KT      8         // 256 / 32 K-tiles
#define NTW     8         // N-tiles per wave (64 tiles / 8 waves)
#define H2P     264       // padded row length (+8 bf16 = 16 B)

typedef short bf16x8 __attribute__((ext_vector_type(8)));
typedef float f32x4  __attribute__((ext_vector_type(4)));

__device__ __forceinline__ float sig_(float x)  { return 1.0f / (1.0f + __expf(-x)); }
__device__ __forceinline__ float tanh_(float x) { return 1.0f - 2.0f / (__expf(2.0f * x) + 1.0f); }
__device__ __forceinline__ unsigned rne16(float f) {
    union { float f; unsigned u; } v; v.f = f;
    return (v.u + 0x7FFFu + ((v.u >> 16) & 1u)) >> 16;
}
__device__ __forceinline__ float u2f(unsigned u) {
    union { unsigned u; float f; } v; v.u = u; return v.f;
}

// Pack W_h into MFMA B-fragment order.
// Wp[tile*64 + lane] (uint4), tile = n*8 + kt  (n: N-tile 0..63, kt: K-tile 0..7)
// dword d of lane l packs W[kt*32+(l>>4)*8+2d][n*16+(l&15)] (lo) and k+1 (hi).
__global__ __launch_bounds__(256)
void pack_wh(const float* __restrict__ Wh, uint4* __restrict__ Wp) {
    int i    = blockIdx.x * 256 + threadIdx.x;   // [0, 32768)
    int tile = i >> 6, lane = i & 63;
    int n  = tile >> 3, kt = tile & 7;
    int k0 = kt * 32 + ((lane >> 4) * 8);
    int col = n * 16 + (lane & 15);
    const float* base = Wh + (size_t)k0 * GDIM + col;   // element j at base[j*GDIM]
    unsigned p0 = rne16(base[0 * GDIM]) | (rne16(base[1 * GDIM]) << 16);
    unsigned p1 = rne16(base[2 * GDIM]) | (rne16(base[3 * GDIM]) << 16);
    unsigned p2 = rne16(base[4 * GDIM]) | (rne16(base[5 * GDIM]) << 16);
    unsigned p3 = rne16(base[6 * GDIM]) | (rne16(base[7 * GDIM]) << 16);
    Wp[i] = make_uint4(p0, p1, p2, p3);
}

__global__ __launch_bounds__(THREADS, 2)
void lstm_scan(const int* __restrict__ tokens,
               const float* __restrict__ Wx,    // [128,1024]
               const uint4* __restrict__ Wp,    // packed bf16 B-frags (ws)
               const float* __restrict__ bias,  // [1024]
               const float* __restrict__ Wd,    // [256,128]
               const float* __restrict__ bd,    // [128]
               float* __restrict__ out)         // [512,128]
{
    __shared__ short h2hi[16][H2P];   // 8.25 KB  bf16 hi part of h (rows 2..15 zero)
    __shared__ short h2lo[16][H2P];   // 8.25 KB  bf16 lo residual
    __shared__ float h32[BC][U];      // 2 KB     fp32 h for final dense
    __shared__ float G2[BC][GDIM];    // 8 KB     gates [row][col]
    __shared__ int   tok[BC][SEQ];    // 8 KB

    const int tid  = threadIdx.x;
    const int r0   = blockIdx.x * BC;
    const int lane = tid & 63;
    const int w    = tid >> 6;        // wave 0..7
    const int m    = lane & 15;
    const int quad = lane >> 4;
    const int uu   = tid & 255;       // update unit
    const int ur   = tid >> 8;        // update row (0/1)

    for (int i = tid; i < BC * SEQ; i += THREADS)
        ((int*)tok)[i] = tokens[r0 * SEQ + i];
    for (int i = tid; i < 16 * H2P; i += THREADS) {
        ((short*)h2hi)[i] = 0;
        ((short*)h2lo)[i] = 0;
    }
    ((float*)h32)[tid] = 0.0f;

    const float b_i = bias[uu];
    const float b_j = bias[U + uu];
    const float b_f = bias[2 * U + uu] + 1.0f;    // forget_bias folded in
    const float b_o = bias[3 * U + uu];
    float c_state = 0.0f;

    const short* ahi = &h2hi[m][quad * 8];
    const short* alo = &h2lo[m][quad * 8];
    const uint4* wbase = Wp + (size_t)w * (NTW * KT * 64) + lane;

    __syncthreads();

    for (int t = 0; t < SEQ; ++t) {
        // prefetch W_x row for the update phase (coalesced, L2)
        const int xr = tok[ur][t];
        const float* wxp = Wx + (size_t)xr * GDIM + uu;
        const float wxi = wxp[0], wxj = wxp[U], wxf = wxp[2 * U], wxo = wxp[3 * U];

        // A-fragments for all 8 K-tiles (hi + lo)
        bf16x8 Ah[KT], Al[KT];
        #pragma unroll
        for (int kt = 0; kt < KT; ++kt) {
            Ah[kt] = *(const bf16x8*)(ahi + kt * 32);
            Al[kt] = *(const bf16x8*)(alo + kt * 32);
        }

        // GEMM: this wave owns N-tiles w*8 .. w*8+7
        #pragma unroll
        for (int nt = 0; nt < NTW; ++nt) {
            const uint4* tb = wbase + nt * (KT * 64);
            f32x4 accH = {0.f, 0.f, 0.f, 0.f};
            f32x4 accL = {0.f, 0.f, 0.f, 0.f};
            #pragma unroll
            for (int kt = 0; kt < KT; ++kt) {
                union { uint4 u; bf16x8 v; } bu;
                bu.u = tb[kt * 64];
                accH = __builtin_amdgcn_mfma_f32_16x16x32_bf16(Ah[kt], bu.v, accH, 0, 0, 0);
                accL = __builtin_amdgcn_mfma_f32_16x16x32_bf16(Al[kt], bu.v, accL, 0, 0, 0);
            }
            if (quad == 0) {     // rows 0,1 live in lanes 0-15, regs 0,1
                const int c = (w * NTW + nt) * 16 + m;
                G2[0][c] = accH[0] + accL[0];
                G2[1][c] = accH[1] + accL[1];
            }
        }
        __syncthreads();

        // LSTM update (gate order i, j, f, o)
        {
            float gi = G2[ur][uu]         + wxi + b_i;
            float gj = G2[ur][U + uu]     + wxj + b_j;
            float gf = G2[ur][2 * U + uu] + wxf + b_f;
            float go = G2[ur][3 * U + uu] + wxo + b_o;
            c_state = c_state * sig_(gf) + sig_(gi) * tanh_(gj);
            float nh = tanh_(c_state) * sig_(go);
            h32[ur][uu] = nh;
            unsigned hi = rne16(nh);
            float lo = nh - u2f(hi << 16);
            h2hi[ur][uu] = (short)hi;
            h2lo[ur][uu] = (short)rne16(lo);
        }
        __syncthreads();
    }

    // final dense
    if (tid < BC * NC) {
        const int r = tid >> 7;
        const int n = tid & (NC - 1);
        float sum = bd[n];
        #pragma unroll 4
        for (int k = 0; k < U; ++k)
            sum = fmaf(h32[r][k], Wd[k * NC + n], sum);
        out[(r0 + r) * NC + n] = sum;
    }
}

extern "C" void kernel_launch(void* const* d_in, const int* in_sizes, int n_in,
                              void* d_out, int out_size, void* d_ws, size_t ws_size,
                              hipStream_t stream) {
    const int*   tokens = (const int*)d_in[0];
    const float* Wx     = (const float*)d_in[1];
    const float* Wh     = (const float*)d_in[2];
    const float* bias   = (const float*)d_in[3];
    const float* Wd     = (const float*)d_in[4];
    const float* bd     = (const float*)d_in[5];
    float*       out    = (float*)d_out;

    uint4* Wp = (uint4*)d_ws;   // 512 KB packed W_h (ws_size proven >= 512 KB in r3-r5)
    pack_wh<<<128, 256, 0, stream>>>(Wh, Wp);
    lstm_scan<<<B_TOT / BC, THREADS, 0, stream>>>(tokens, Wx, Wp, bias, Wd, bd, out);
}